// Round 2
// baseline (3921.129 us; speedup 1.0000x reference)
//
#include <hip/hip_runtime.h>
#include <math.h>

// LSTM anomaly scan, B=256 T=1024 I=8 H=164 O=1, WL=0, THRESH=0.1.
// One block (704 thr = 11 waves) per batch element, sequential t-loop.
// Thread j owns gate row j.
//
// ROOT CAUSE found in rounds 0/1: the "register-resident" W_hh cols were
// never resident. Round 0: allocator (capped ~80 regs by its occupancy
// heuristic) rematerialized the loop-invariant weight loads INSIDE the
// t-loop => streamed 273 KB/step/CU from L2 (23.8 TB/s aggregate ~ L2
// roofline). Round 1: asm pins forced materialization but the allocator
// SPILLED to scratch instead (VGPR=84 + cache-resident scratch traffic).
//
// Fix: pin occupancy exactly with amdgpu_waves_per_eu(3,3) (budget =
// floor(512/3) = 170 regs) + asm pins (remat illegal) + working set
// trimmed so demand ~164 fits. Structure otherwise = round-0 (flat gate
// LDS layout: zero bank conflicts; h broadcast via v_readlane of
// redundant per-wave state; ONE barrier/step) + round-1's unified
// activation (tanh rows pre-doubled => single sigmoid path) and
// rcp+Newton division, with overflow clamp on exp.

typedef __attribute__((ext_vector_type(4))) float f4;

namespace {
constexpr int kB = 256;
constexpr int kT = 1024;
constexpr int kI = 8;
constexpr int kH = 164;
constexpr int kG = 4 * kH;                 // 656
constexpr int kThreads = 704;              // 11 waves
constexpr int kRegK = 104;                 // W_hh cols in VGPRs (26 float4)
constexpr int kTailC = (kH - kRegK) / 4;   // 15 LDS planes (cols 104..163)
constexpr float kThresh = 0.1f;

__device__ __forceinline__ float rlane(float v, int l) {
    return __int_as_float(__builtin_amdgcn_readlane(__float_as_int(v), l));
}
__device__ __forceinline__ float hb(float h0, float h1, float h2, int k) {
    return (k < 64) ? rlane(h0, k)
         : (k < 128) ? rlane(h1, k - 64)
                     : rlane(h2, k - 128);
}
template <int CTRL>
__device__ __forceinline__ float dpp_add(float x) {
    int t = __builtin_amdgcn_update_dpp(0, __float_as_int(x), CTRL, 0xf, 0xf, true);
    return __int_as_float(t);
}
// full-wave sum, result broadcast via lane 63 (lands in SGPR)
__device__ __forceinline__ float wave_sum(float x) {
    x += dpp_add<0x111>(x);   // row_shr:1
    x += dpp_add<0x112>(x);   // row_shr:2
    x += dpp_add<0x114>(x);   // row_shr:4
    x += dpp_add<0x118>(x);   // row_shr:8
    x += dpp_add<0x142>(x);   // row_bcast:15
    x += dpp_add<0x143>(x);   // row_bcast:31
    return rlane(x, 63);
}
// rcp + one Newton iteration: ~0.5 ulp at 3 instructions
__device__ __forceinline__ float fast_rcp(float d) {
    float r = __builtin_amdgcn_rcpf(d);
    float e = fmaf(-d, r, 1.0f);
    return fmaf(r, e, r);
}
// sigma(x) with overflow-safe clamp (inf exp would NaN the Newton step)
__device__ __forceinline__ float sigm_c(float x) {
    float e = fminf(__expf(-x), 3.0e38f);
    return fast_rcp(1.0f + e);
}
// tanh(x) = 2*sigma(2x) - 1
__device__ __forceinline__ float tanh_c(float x) {
    return fmaf(2.0f, sigm_c(2.0f * x), -1.0f);
}
} // namespace

__global__
__attribute__((amdgpu_flat_work_group_size(kThreads, kThreads)))
__attribute__((amdgpu_waves_per_eu(3, 3)))
void lstm_anom_kernel(
    const float* __restrict__ x,     // (B,T,I)
    const float* __restrict__ Wih,   // (4H,I)
    const float* __restrict__ Whh,   // (4H,H)
    const float* __restrict__ bih,   // (4H)
    const float* __restrict__ bhh,   // (4H)
    const float* __restrict__ Wout,  // (1,H)
    const float* __restrict__ bout,  // (1)
    float* __restrict__ out)         // preds (B,T) then flags (B,T)
{
    __shared__ f4    wp[kTailC * kG];   // 15*656*16 = 157440 B
    __shared__ float gates[2][kG];      // 5248 B  (total 162688 B)

    const int tid  = threadIdx.x;
    const int lane = tid & 63;
    const int b    = blockIdx.x;
    const int jj   = (tid < kG) ? tid : (kG - 1);
    const int gate = jj / kH;             // 0=i 1=f 2=g 3=o
    const bool is_tanh = (gate == 2);
    const float wscl = is_tanh ? 2.0f : 1.0f;

    // ---- stage W_hh tail planes (cols 104..163); tanh rows pre-doubled ----
    // round-0 index layout (plane-major): zero-conflict stride-16B reads.
    for (int i = tid; i < kTailC * kG; i += kThreads) {
        const int c = i / kG, r = i - c * kG;
        f4 v = *(const f4*)(Whh + (size_t)r * kH + kRegK + 4 * c);
        if (r >= 2 * kH && r < 3 * kH) v *= 2.0f;
        wp[i] = v;
    }

    // ---- per-thread resident weights, asm-pinned against remat ----
    f4 wih0 = ((const f4*)(Wih + (size_t)jj * kI))[0] * wscl;
    f4 wih1 = ((const f4*)(Wih + (size_t)jj * kI))[1] * wscl;
    asm volatile("" : "+v"(wih0), "+v"(wih1));
    f4 whh[kRegK / 4];
    #pragma unroll
    for (int k = 0; k < kRegK / 4; ++k) {
        whh[k] = ((const f4*)(Whh + (size_t)jj * kH))[k] * wscl;
        asm volatile("" : "+v"(whh[k]));
    }
    float bsum = (bih[jj] + bhh[jj]) * wscl;
    asm volatile("" : "+v"(bsum));
    const int   u2   = (lane < kH - 128) ? (128 + lane) : (kH - 1); // clamp
    float wo0 = Wout[lane];
    float wo1 = Wout[64 + lane];
    float wo2 = (128 + lane < kH) ? Wout[128 + lane] : 0.0f;        // kills dup
    asm volatile("" : "+v"(wo0), "+v"(wo1), "+v"(wo2));
    const float bo = bout[0];

    // redundant per-wave state: units lane, 64+lane, u2
    float vc0 = 0.f, vc1 = 0.f, vc2 = 0.f;
    float vh0 = 0.f, vh1 = 0.f, vh2 = 0.f;
    float pred = 0.f;

    const float* xb = x + (size_t)b * kT * kI;
    float* pred_out = out + (size_t)b * kT;
    float* flag_out = out + (size_t)kB * kT + (size_t)b * kT;

    // 3 LDS base pointers keep all tail ds_read offsets within imm range
    const f4* wt0 = wp + jj;
    const f4* wt5 = wp + 5 * kG + jj;
    const f4* wtA = wp + 10 * kG + jj;

    f4 xa = ((const f4*)xb)[0];
    f4 xc = ((const f4*)xb)[1];

    __syncthreads();

    for (int t = 0; t < kT; ++t) {
        const bool  anom = (t > 0) && (fabsf(pred - xa.x) > kThresh);
        const float x0e  = anom ? pred : xa.x;

        // ---- x-part: 4 independent accumulators; xa/xc die here ----
        float a0 = fmaf(x0e, wih0.x, bsum);
        float a1 = xa.y * wih0.y;
        float a2 = xa.z * wih0.z;
        float a3 = xa.w * wih0.w;
        a0 = fmaf(xc.x, wih1.x, a0);
        a1 = fmaf(xc.y, wih1.y, a1);
        a2 = fmaf(xc.z, wih1.z, a2);
        a3 = fmaf(xc.w, wih1.w, a3);

        // prefetch x[t+1]: FMA loop hides the latency
        const f4* nx = (const f4*)(xb + (size_t)((t + 1 < kT) ? t + 1 : t) * kI);
        f4 na = nx[0];
        f4 nc = nx[1];

        // LDS tail prefetch, 3 deep (12 regs, bounded lookahead)
        f4 t0 = wt0[0];
        f4 t1 = wt0[kG];
        f4 t2 = wt0[2 * kG];

        #define GRP(W, KB) \
            a0 = fmaf(hb(vh0, vh1, vh2, (KB) + 0), (W).x, a0); \
            a1 = fmaf(hb(vh0, vh1, vh2, (KB) + 1), (W).y, a1); \
            a2 = fmaf(hb(vh0, vh1, vh2, (KB) + 2), (W).z, a2); \
            a3 = fmaf(hb(vh0, vh1, vh2, (KB) + 3), (W).w, a3);

        #pragma unroll
        for (int kk = 0; kk < kRegK / 4; ++kk) {
            GRP(whh[kk], kk * 4);
        }
        #pragma unroll
        for (int c = 0; c < kTailC; ++c) {
            f4 w;
            if (c % 3 == 0) w = t0; else if (c % 3 == 1) w = t1; else w = t2;
            const int cn = c + 3;
            if (cn < kTailC) {
                const f4 ld = (cn < 5)  ? wt0[cn * kG]
                            : (cn < 10) ? wt5[(cn - 5) * kG]
                                        : wtA[(cn - 10) * kG];
                if (c % 3 == 0) t0 = ld; else if (c % 3 == 1) t1 = ld; else t2 = ld;
            }
            GRP(w, kRegK + c * 4);
        }
        #undef GRP

        // ---- unified activation: rows pre-doubled => sigma path only ----
        const float acc = (a0 + a1) + (a2 + a3);
        const float yy  = sigm_c(acc);
        const float av  = is_tanh ? fmaf(2.0f, yy, -1.0f) : yy;

        // flat gate layout: stride-4B writes/reads, zero bank conflicts
        float* gw = gates[t & 1];
        if (tid < kG) gw[jj] = av;
        __syncthreads();

        // ---- redundant cell/h update in every wave (no 2nd barrier) ----
        const float* gb = gates[t & 1];
        float iv0 = gb[lane],          iv1 = gb[64 + lane],          iv2 = gb[u2];
        float fv0 = gb[kH + lane],     fv1 = gb[kH + 64 + lane],     fv2 = gb[kH + u2];
        float gv0 = gb[2*kH + lane],   gv1 = gb[2*kH + 64 + lane],   gv2 = gb[2*kH + u2];
        float ov0 = gb[3*kH + lane],   ov1 = gb[3*kH + 64 + lane],   ov2 = gb[3*kH + u2];
        vc0 = fmaf(fv0, vc0, iv0 * gv0);  vh0 = ov0 * tanh_c(vc0);
        vc1 = fmaf(fv1, vc1, iv1 * gv1);  vh1 = ov1 * tanh_c(vc1);
        vc2 = fmaf(fv2, vc2, iv2 * gv2);  vh2 = ov2 * tanh_c(vc2);

        // ---- pred (identical in every wave; DPP reduce, VALU only) ----
        const float p = fmaf(vh0, wo0, fmaf(vh1, wo1, vh2 * wo2));
        pred = wave_sum(p) + bo;

        if (tid == 0) {
            pred_out[t] = pred;
            flag_out[t] = anom ? 1.0f : 0.0f;
        }
        xa = na;
        xc = nc;
    }
}

extern "C" void kernel_launch(void* const* d_in, const int* in_sizes, int n_in,
                              void* d_out, int out_size, void* d_ws, size_t ws_size,
                              hipStream_t stream) {
    const float* x    = (const float*)d_in[0];
    const float* Wih  = (const float*)d_in[1];
    const float* Whh  = (const float*)d_in[2];
    const float* bih  = (const float*)d_in[3];
    const float* bhh  = (const float*)d_in[4];
    const float* Wout = (const float*)d_in[5];
    const float* bout = (const float*)d_in[6];
    lstm_anom_kernel<<<dim3(kB), dim3(kThreads), 0, stream>>>(
        x, Wih, Whh, bih, bhh, Wout, bout, (float*)d_out);
}

// Round 3
// 2825.026 us; speedup vs baseline: 1.3880x; 1.3880x over previous
//
#include <hip/hip_runtime.h>
#include <math.h>

// LSTM anomaly scan, B=256 T=1024 I=8 H=164 O=1, WL=0, THRESH=0.1.
// One block (704 thr = 11 waves) per batch element, sequential t-loop.
// Thread j owns gate row j.
//
// Capacity post-mortem (r0-r2): full W residency is infeasible — W_hh is
// 430 KB vs 512 KB physical regfile/CU; the allocator's fallbacks are
// remat (r0: re-streams 273 KB/step from L2, 2.0 us/step L2 wall) or
// spill (r1/r2: worse). This version embraces streaming but shrinks and
// overlaps it:
//   - LDS: 60 cols (104..163), 15 planes, proven 0-conflict layout.
//   - Regs: only 32 cols (8 float4) pinned — small enough to actually fit
//     (demand ~140 < 170 budget at 11 waves).
//   - Streamed: 72 cols (32..103) = 18 dwordx4/step off ONE base pointer
//     (imm offsets, no per-step addr VALU), 3 batches of 6 interleaved
//     with FMA groups => L2 latency hidden under compute; sequential 16B
//     loads share 64B lines so L1 serves 3 of every 4 requests.
//   - L2 stream: 189 KB/step/block; 32 blocks/XCD -> ~1.4 us/step wall,
//     below VALU time => VALU-bound with stream overlapped.
// Skeleton unchanged from r0 (proven): ONE barrier/step, flat gate LDS
// (0 conflicts), h broadcast via v_readlane of redundant per-wave state,
// DPP wave-sum pred. Cheap activations (rcp+Newton) validated in r2
// (absmax identical to r0).

typedef __attribute__((ext_vector_type(4))) float f4;

namespace {
constexpr int kB = 256;
constexpr int kT = 1024;
constexpr int kI = 8;
constexpr int kH = 164;
constexpr int kG = 4 * kH;                   // 656
constexpr int kThreads = 704;                // 11 waves
constexpr int kRegC = 8;                     // resident f4 groups (cols 0..31)
constexpr int kStrC = 18;                    // streamed f4 groups (cols 32..103)
constexpr int kStrBase = kRegC * 4;          // 32
constexpr int kLdsBase = kStrBase + kStrC * 4; // 104
constexpr int kLdsC = (kH - kLdsBase) / 4;   // 15 planes (cols 104..163)
constexpr float kThresh = 0.1f;

__device__ __forceinline__ float rlane(float v, int l) {
    return __int_as_float(__builtin_amdgcn_readlane(__float_as_int(v), l));
}
__device__ __forceinline__ float hb(float h0, float h1, float h2, int k) {
    return (k < 64) ? rlane(h0, k)
         : (k < 128) ? rlane(h1, k - 64)
                     : rlane(h2, k - 128);
}
template <int CTRL>
__device__ __forceinline__ float dpp_add(float x) {
    int t = __builtin_amdgcn_update_dpp(0, __float_as_int(x), CTRL, 0xf, 0xf, true);
    return __int_as_float(t);
}
// full-wave sum, result broadcast via lane 63
__device__ __forceinline__ float wave_sum(float x) {
    x += dpp_add<0x111>(x);   // row_shr:1
    x += dpp_add<0x112>(x);   // row_shr:2
    x += dpp_add<0x114>(x);   // row_shr:4
    x += dpp_add<0x118>(x);   // row_shr:8
    x += dpp_add<0x142>(x);   // row_bcast:15
    x += dpp_add<0x143>(x);   // row_bcast:31
    return rlane(x, 63);
}
// rcp + one Newton iteration: ~0.5 ulp at 3 instructions
__device__ __forceinline__ float fast_rcp(float d) {
    float r = __builtin_amdgcn_rcpf(d);
    float e = fmaf(-d, r, 1.0f);
    return fmaf(r, e, r);
}
// sigma(x), overflow-safe (clamp inf exp before Newton step)
__device__ __forceinline__ float sigm_c(float x) {
    float e = fminf(__expf(-x), 3.0e38f);
    return fast_rcp(1.0f + e);
}
// tanh(x) = 2*sigma(2x) - 1
__device__ __forceinline__ float tanh_c(float x) {
    return fmaf(2.0f, sigm_c(2.0f * x), -1.0f);
}
} // namespace

__global__ __launch_bounds__(kThreads, 3) void lstm_anom_kernel(
    const float* __restrict__ x,     // (B,T,I)
    const float* __restrict__ Wih,   // (4H,I)
    const float* __restrict__ Whh,   // (4H,H)
    const float* __restrict__ bih,   // (4H)
    const float* __restrict__ bhh,   // (4H)
    const float* __restrict__ Wout,  // (1,H)
    const float* __restrict__ bout,  // (1)
    float* __restrict__ out)         // preds (B,T) then flags (B,T)
{
    __shared__ f4    wp[kLdsC * kG];    // 15*656*16 = 157440 B
    __shared__ float gates[2][kG];      // 5248 B  (total 162688 B)

    const int tid  = threadIdx.x;
    const int lane = tid & 63;
    const int b    = blockIdx.x;
    const int jj   = (tid < kG) ? tid : (kG - 1);
    const bool is_tanh = (jj >= 2 * kH) && (jj < 3 * kH);

    // ---- stage W_hh tail planes (cols 104..163) ----
    for (int i = tid; i < kLdsC * kG; i += kThreads) {
        const int c = i / kG, r = i - c * kG;
        wp[i] = *(const f4*)(Whh + (size_t)r * kH + kLdsBase + 4 * c);
    }

    // ---- small resident weight set (cols 0..31) + W_ih, pinned ----
    const f4* wrow = (const f4*)(Whh + (size_t)jj * kH);
    f4 w0 = wrow[0], w1 = wrow[1], w2 = wrow[2], w3 = wrow[3];
    f4 w4 = wrow[4], w5 = wrow[5], w6 = wrow[6], w7 = wrow[7];
    f4 wih0 = ((const f4*)(Wih + (size_t)jj * kI))[0];
    f4 wih1 = ((const f4*)(Wih + (size_t)jj * kI))[1];
    asm volatile("" : "+v"(w0), "+v"(w1), "+v"(w2), "+v"(w3),
                      "+v"(w4), "+v"(w5), "+v"(w6), "+v"(w7),
                      "+v"(wih0), "+v"(wih1));
    float bsum = bih[jj] + bhh[jj];
    const int u2 = (lane < kH - 128) ? (128 + lane) : (kH - 1); // clamp
    float wo0 = Wout[lane];
    float wo1 = Wout[64 + lane];
    float wo2 = (128 + lane < kH) ? Wout[128 + lane] : 0.0f;    // kills dup
    asm volatile("" : "+v"(bsum), "+v"(wo0), "+v"(wo1), "+v"(wo2));
    const float bo = bout[0];

    // streamed-cols base: all 18 loads are base + immediate offset
    const f4* ws = (const f4*)(Whh + (size_t)jj * kH + kStrBase);

    // redundant per-wave state: units lane, 64+lane, u2
    float vc0 = 0.f, vc1 = 0.f, vc2 = 0.f;
    float vh0 = 0.f, vh1 = 0.f, vh2 = 0.f;
    float pred = 0.f;

    const float* xb = x + (size_t)b * kT * kI;
    float* pred_out = out + (size_t)b * kT;
    float* flag_out = out + (size_t)kB * kT + (size_t)b * kT;

    // 3 LDS base pointers keep tail ds_read offsets within imm range
    const f4* wt0 = wp + jj;
    const f4* wt5 = wp + 5 * kG + jj;
    const f4* wtA = wp + 10 * kG + jj;

    f4 xa = ((const f4*)xb)[0];
    f4 xc = ((const f4*)xb)[1];

    __syncthreads();

    for (int t = 0; t < kT; ++t) {
        // ---- stream batch A issue (cols 32..55) ----
        f4 sA0 = ws[0],  sA1 = ws[1],  sA2 = ws[2];
        f4 sA3 = ws[3],  sA4 = ws[4],  sA5 = ws[5];

        const bool  anom = (t > 0) && (fabsf(pred - xa.x) > kThresh);
        const float x0e  = anom ? pred : xa.x;

        // ---- x-part: 4 independent accumulators ----
        float a0 = fmaf(x0e, wih0.x, bsum);
        float a1 = xa.y * wih0.y;
        float a2 = xa.z * wih0.z;
        float a3 = xa.w * wih0.w;
        a0 = fmaf(xc.x, wih1.x, a0);
        a1 = fmaf(xc.y, wih1.y, a1);
        a2 = fmaf(xc.z, wih1.z, a2);
        a3 = fmaf(xc.w, wih1.w, a3);

        // ---- stream batch B issue (cols 56..79) ----
        f4 sB0 = ws[6],  sB1 = ws[7],  sB2 = ws[8];
        f4 sB3 = ws[9],  sB4 = ws[10], sB5 = ws[11];

        // prefetch x[t+1]
        const f4* nx = (const f4*)(xb + (size_t)((t + 1 < kT) ? t + 1 : t) * kI);
        f4 na = nx[0];
        f4 nc = nx[1];

        #define GRP(W, KB) \
            a0 = fmaf(hb(vh0, vh1, vh2, (KB) + 0), (W).x, a0); \
            a1 = fmaf(hb(vh0, vh1, vh2, (KB) + 1), (W).y, a1); \
            a2 = fmaf(hb(vh0, vh1, vh2, (KB) + 2), (W).z, a2); \
            a3 = fmaf(hb(vh0, vh1, vh2, (KB) + 3), (W).w, a3);

        // ---- resident FMAs (cols 0..31), stream latency hides here ----
        GRP(w0, 0)  GRP(w1, 4)  GRP(w2, 8)  GRP(w3, 12)
        GRP(w4, 16) GRP(w5, 20) GRP(w6, 24) GRP(w7, 28)

        // ---- batch A FMAs (cols 32..55) ----
        GRP(sA0, 32) GRP(sA1, 36) GRP(sA2, 40)
        GRP(sA3, 44) GRP(sA4, 48) GRP(sA5, 52)

        // ---- stream batch C issue (cols 80..103) ----
        f4 sC0 = ws[12], sC1 = ws[13], sC2 = ws[14];
        f4 sC3 = ws[15], sC4 = ws[16], sC5 = ws[17];

        // ---- batch B FMAs (cols 56..79) ----
        GRP(sB0, 56) GRP(sB1, 60) GRP(sB2, 64)
        GRP(sB3, 68) GRP(sB4, 72) GRP(sB5, 76)

        // ---- batch C FMAs (cols 80..103) ----
        GRP(sC0, 80) GRP(sC1, 84) GRP(sC2, 88)
        GRP(sC3, 92) GRP(sC4, 96) GRP(sC5, 100)

        // ---- LDS tail (cols 104..163), compiler pipelines lgkmcnt ----
        #pragma unroll
        for (int c = 0; c < kLdsC; ++c) {
            const f4 w = (c < 5)  ? wt0[c * kG]
                       : (c < 10) ? wt5[(c - 5) * kG]
                                  : wtA[(c - 10) * kG];
            GRP(w, kLdsBase + c * 4)
        }
        #undef GRP

        // ---- activation ----
        const float acc = (a0 + a1) + (a2 + a3);
        const float av  = is_tanh ? tanh_c(acc) : sigm_c(acc);

        float* gw = gates[t & 1];
        if (tid < kG) gw[jj] = av;
        __syncthreads();

        // ---- redundant cell/h update in every wave (no 2nd barrier) ----
        const float* gb = gates[t & 1];
        float iv0 = gb[lane],          iv1 = gb[64 + lane],          iv2 = gb[u2];
        float fv0 = gb[kH + lane],     fv1 = gb[kH + 64 + lane],     fv2 = gb[kH + u2];
        float gv0 = gb[2*kH + lane],   gv1 = gb[2*kH + 64 + lane],   gv2 = gb[2*kH + u2];
        float ov0 = gb[3*kH + lane],   ov1 = gb[3*kH + 64 + lane],   ov2 = gb[3*kH + u2];
        vc0 = fmaf(fv0, vc0, iv0 * gv0);  vh0 = ov0 * tanh_c(vc0);
        vc1 = fmaf(fv1, vc1, iv1 * gv1);  vh1 = ov1 * tanh_c(vc1);
        vc2 = fmaf(fv2, vc2, iv2 * gv2);  vh2 = ov2 * tanh_c(vc2);

        // ---- pred (identical in every wave; DPP reduce, VALU only) ----
        const float p = fmaf(vh0, wo0, fmaf(vh1, wo1, vh2 * wo2));
        pred = wave_sum(p) + bo;

        if (tid == 0) {
            pred_out[t] = pred;
            flag_out[t] = anom ? 1.0f : 0.0f;
        }
        xa = na;
        xc = nc;
    }
}

extern "C" void kernel_launch(void* const* d_in, const int* in_sizes, int n_in,
                              void* d_out, int out_size, void* d_ws, size_t ws_size,
                              hipStream_t stream) {
    const float* x    = (const float*)d_in[0];
    const float* Wih  = (const float*)d_in[1];
    const float* Whh  = (const float*)d_in[2];
    const float* bih  = (const float*)d_in[3];
    const float* bhh  = (const float*)d_in[4];
    const float* Wout = (const float*)d_in[5];
    const float* bout = (const float*)d_in[6];
    lstm_anom_kernel<<<dim3(kB), dim3(kThreads), 0, stream>>>(
        x, Wih, Whh, bih, bhh, Wout, bout, (float*)d_out);
}

// Round 4
// 2808.703 us; speedup vs baseline: 1.3961x; 1.0058x over previous
//
#include <hip/hip_runtime.h>
#include <math.h>

// LSTM anomaly scan, B=256 T=1024 I=8 H=164 O=1, WL=0, THRESH=0.1.
// One block (704 thr = 11 waves) per batch element, sequential t-loop.
// Thread j owns gate row j.
//
// Calibrated per-step per-CU model (cycles): L2 stream = streamKB/56 B/cy;
// VALU ~2100; LDS ~1900. r0 (273 KB stream): wall 4875, meas 7050.
// r3 (189 KB): wall 3375, meas 6900. Stream is dominant and the pin
// boundary is the lever. r3 proved 8x f4 pins HOLD (VGPR=76=40 pinned+36)
// while r1/r2's 26x f4 (104+60~=164 at the 170 edge) spilled. This round:
// 16x f4 pinned (cols 0..63, 76 pinned floats + ~55 working ~= 130 << 170),
// stream only 40 cols (64..103) = 105 KB/step -> wall 1875 cy, below VALU
// ~2100 => VALU becomes the binding constraint.
// Consumption order pinned -> LDS tail -> stream gives stream loads ~500 cy
// of FMA cover (r3 gave batch A only ~130 cy).
// Skeleton (proven, absmax 2.44e-4): ONE barrier/step, flat gate LDS
// (0 conflicts), h broadcast via v_readlane of redundant per-wave state,
// DPP wave-sum pred, rcp+Newton activations with overflow clamp.

typedef __attribute__((ext_vector_type(4))) float f4;

namespace {
constexpr int kB = 256;
constexpr int kT = 1024;
constexpr int kI = 8;
constexpr int kH = 164;
constexpr int kG = 4 * kH;                     // 656
constexpr int kThreads = 704;                  // 11 waves
constexpr int kRegC = 16;                      // pinned f4 groups (cols 0..63)
constexpr int kStrC = 10;                      // streamed f4 groups (cols 64..103)
constexpr int kStrBase = kRegC * 4;            // 64
constexpr int kLdsBase = kStrBase + kStrC * 4; // 104
constexpr int kLdsC = (kH - kLdsBase) / 4;     // 15 planes (cols 104..163)
constexpr float kThresh = 0.1f;

__device__ __forceinline__ float rlane(float v, int l) {
    return __int_as_float(__builtin_amdgcn_readlane(__float_as_int(v), l));
}
__device__ __forceinline__ float hb(float h0, float h1, float h2, int k) {
    return (k < 64) ? rlane(h0, k)
         : (k < 128) ? rlane(h1, k - 64)
                     : rlane(h2, k - 128);
}
template <int CTRL>
__device__ __forceinline__ float dpp_add(float x) {
    int t = __builtin_amdgcn_update_dpp(0, __float_as_int(x), CTRL, 0xf, 0xf, true);
    return __int_as_float(t);
}
// full-wave sum, result broadcast via lane 63
__device__ __forceinline__ float wave_sum(float x) {
    x += dpp_add<0x111>(x);   // row_shr:1
    x += dpp_add<0x112>(x);   // row_shr:2
    x += dpp_add<0x114>(x);   // row_shr:4
    x += dpp_add<0x118>(x);   // row_shr:8
    x += dpp_add<0x142>(x);   // row_bcast:15
    x += dpp_add<0x143>(x);   // row_bcast:31
    return rlane(x, 63);
}
// rcp + one Newton iteration: ~0.5 ulp at 3 instructions
__device__ __forceinline__ float fast_rcp(float d) {
    float r = __builtin_amdgcn_rcpf(d);
    float e = fmaf(-d, r, 1.0f);
    return fmaf(r, e, r);
}
// sigma(x), overflow-safe (clamp inf exp before Newton step)
__device__ __forceinline__ float sigm_c(float x) {
    float e = fminf(__expf(-x), 3.0e38f);
    return fast_rcp(1.0f + e);
}
// tanh(x) = 2*sigma(2x) - 1
__device__ __forceinline__ float tanh_c(float x) {
    return fmaf(2.0f, sigm_c(2.0f * x), -1.0f);
}
} // namespace

__global__
__attribute__((amdgpu_flat_work_group_size(kThreads, kThreads)))
__attribute__((amdgpu_waves_per_eu(3, 3)))
void lstm_anom_kernel(
    const float* __restrict__ x,     // (B,T,I)
    const float* __restrict__ Wih,   // (4H,I)
    const float* __restrict__ Whh,   // (4H,H)
    const float* __restrict__ bih,   // (4H)
    const float* __restrict__ bhh,   // (4H)
    const float* __restrict__ Wout,  // (1,H)
    const float* __restrict__ bout,  // (1)
    float* __restrict__ out)         // preds (B,T) then flags (B,T)
{
    __shared__ f4    wp[kLdsC * kG];    // 15*656*16 = 157440 B
    __shared__ float gates[2][kG];      // 5248 B  (total 162688 B)

    const int tid  = threadIdx.x;
    const int lane = tid & 63;
    const int b    = blockIdx.x;
    const int jj   = (tid < kG) ? tid : (kG - 1);
    const bool is_tanh = (jj >= 2 * kH) && (jj < 3 * kH);

    // ---- stage W_hh tail planes (cols 104..163) ----
    for (int i = tid; i < kLdsC * kG; i += kThreads) {
        const int c = i / kG, r = i - c * kG;
        wp[i] = *(const f4*)(Whh + (size_t)r * kH + kLdsBase + 4 * c);
    }

    // ---- pinned weight set: cols 0..63 (16 f4) + W_ih (2 f4) ----
    const f4* wrow = (const f4*)(Whh + (size_t)jj * kH);
    f4 w0 = wrow[0],  w1 = wrow[1],  w2 = wrow[2],  w3 = wrow[3];
    f4 w4 = wrow[4],  w5 = wrow[5],  w6 = wrow[6],  w7 = wrow[7];
    f4 w8 = wrow[8],  w9 = wrow[9],  wA = wrow[10], wB = wrow[11];
    f4 wC = wrow[12], wD = wrow[13], wE = wrow[14], wF = wrow[15];
    f4 wih0 = ((const f4*)(Wih + (size_t)jj * kI))[0];
    f4 wih1 = ((const f4*)(Wih + (size_t)jj * kI))[1];
    asm volatile("" : "+v"(w0), "+v"(w1), "+v"(w2), "+v"(w3),
                      "+v"(w4), "+v"(w5), "+v"(w6), "+v"(w7),
                      "+v"(w8), "+v"(w9), "+v"(wA), "+v"(wB),
                      "+v"(wC), "+v"(wD), "+v"(wE), "+v"(wF),
                      "+v"(wih0), "+v"(wih1));
    float bsum = bih[jj] + bhh[jj];
    const int u2 = (lane < kH - 128) ? (128 + lane) : (kH - 1); // clamp
    float wo0 = Wout[lane];
    float wo1 = Wout[64 + lane];
    float wo2 = (128 + lane < kH) ? Wout[128 + lane] : 0.0f;    // kills dup
    asm volatile("" : "+v"(bsum), "+v"(wo0), "+v"(wo1), "+v"(wo2));
    const float bo = bout[0];

    // streamed cols 64..103: all loads are base + immediate offset
    const f4* ws = (const f4*)(Whh + (size_t)jj * kH + kStrBase);

    // redundant per-wave state: units lane, 64+lane, u2
    float vc0 = 0.f, vc1 = 0.f, vc2 = 0.f;
    float vh0 = 0.f, vh1 = 0.f, vh2 = 0.f;
    float pred = 0.f;

    const float* xb = x + (size_t)b * kT * kI;
    float* pred_out = out + (size_t)b * kT;
    float* flag_out = out + (size_t)kB * kT + (size_t)b * kT;

    // 3 LDS base pointers keep tail ds_read offsets within imm range
    const f4* wt0 = wp + jj;
    const f4* wt5 = wp + 5 * kG + jj;
    const f4* wtA = wp + 10 * kG + jj;

    f4 xa = ((const f4*)xb)[0];
    f4 xc = ((const f4*)xb)[1];

    __syncthreads();

    for (int t = 0; t < kT; ++t) {
        // ---- stream batch A issue (cols 64..83): consumed LAST ----
        f4 sA0 = ws[0], sA1 = ws[1], sA2 = ws[2], sA3 = ws[3], sA4 = ws[4];

        const bool  anom = (t > 0) && (fabsf(pred - xa.x) > kThresh);
        const float x0e  = anom ? pred : xa.x;

        // ---- x-part: 4 independent accumulators ----
        float a0 = fmaf(x0e, wih0.x, bsum);
        float a1 = xa.y * wih0.y;
        float a2 = xa.z * wih0.z;
        float a3 = xa.w * wih0.w;
        a0 = fmaf(xc.x, wih1.x, a0);
        a1 = fmaf(xc.y, wih1.y, a1);
        a2 = fmaf(xc.z, wih1.z, a2);
        a3 = fmaf(xc.w, wih1.w, a3);

        // ---- stream batch B issue (cols 84..103) ----
        f4 sB0 = ws[5], sB1 = ws[6], sB2 = ws[7], sB3 = ws[8], sB4 = ws[9];

        // prefetch x[t+1]
        const f4* nx = (const f4*)(xb + (size_t)((t + 1 < kT) ? t + 1 : t) * kI);
        f4 na = nx[0];
        f4 nc = nx[1];

        #define GRP(W, KB) \
            a0 = fmaf(hb(vh0, vh1, vh2, (KB) + 0), (W).x, a0); \
            a1 = fmaf(hb(vh0, vh1, vh2, (KB) + 1), (W).y, a1); \
            a2 = fmaf(hb(vh0, vh1, vh2, (KB) + 2), (W).z, a2); \
            a3 = fmaf(hb(vh0, vh1, vh2, (KB) + 3), (W).w, a3);

        // ---- pinned FMAs (cols 0..63): stream latency hides here ----
        GRP(w0, 0)  GRP(w1, 4)  GRP(w2, 8)  GRP(w3, 12)
        GRP(w4, 16) GRP(w5, 20) GRP(w6, 24) GRP(w7, 28)
        GRP(w8, 32) GRP(w9, 36) GRP(wA, 40) GRP(wB, 44)
        GRP(wC, 48) GRP(wD, 52) GRP(wE, 56) GRP(wF, 60)

        // ---- LDS tail (cols 104..163): more stream cover ----
        #pragma unroll
        for (int c = 0; c < kLdsC; ++c) {
            const f4 w = (c < 5)  ? wt0[c * kG]
                       : (c < 10) ? wt5[(c - 5) * kG]
                                  : wtA[(c - 10) * kG];
            GRP(w, kLdsBase + c * 4)
        }

        // ---- stream FMAs (cols 64..103), loads long since landed ----
        GRP(sA0, 64) GRP(sA1, 68) GRP(sA2, 72) GRP(sA3, 76) GRP(sA4, 80)
        GRP(sB0, 84) GRP(sB1, 88) GRP(sB2, 92) GRP(sB3, 96) GRP(sB4, 100)
        #undef GRP

        // ---- activation ----
        const float acc = (a0 + a1) + (a2 + a3);
        const float av  = is_tanh ? tanh_c(acc) : sigm_c(acc);

        float* gw = gates[t & 1];
        if (tid < kG) gw[jj] = av;
        __syncthreads();

        // ---- redundant cell/h update in every wave (no 2nd barrier) ----
        const float* gb = gates[t & 1];
        float iv0 = gb[lane],          iv1 = gb[64 + lane],          iv2 = gb[u2];
        float fv0 = gb[kH + lane],     fv1 = gb[kH + 64 + lane],     fv2 = gb[kH + u2];
        float gv0 = gb[2*kH + lane],   gv1 = gb[2*kH + 64 + lane],   gv2 = gb[2*kH + u2];
        float ov0 = gb[3*kH + lane],   ov1 = gb[3*kH + 64 + lane],   ov2 = gb[3*kH + u2];
        vc0 = fmaf(fv0, vc0, iv0 * gv0);  vh0 = ov0 * tanh_c(vc0);
        vc1 = fmaf(fv1, vc1, iv1 * gv1);  vh1 = ov1 * tanh_c(vc1);
        vc2 = fmaf(fv2, vc2, iv2 * gv2);  vh2 = ov2 * tanh_c(vc2);

        // ---- pred (identical in every wave; DPP reduce, VALU only) ----
        const float p = fmaf(vh0, wo0, fmaf(vh1, wo1, vh2 * wo2));
        pred = wave_sum(p) + bo;

        if (tid == 0) {
            pred_out[t] = pred;
            flag_out[t] = anom ? 1.0f : 0.0f;
        }
        xa = na;
        xc = nc;
    }
}

extern "C" void kernel_launch(void* const* d_in, const int* in_sizes, int n_in,
                              void* d_out, int out_size, void* d_ws, size_t ws_size,
                              hipStream_t stream) {
    const float* x    = (const float*)d_in[0];
    const float* Wih  = (const float*)d_in[1];
    const float* Whh  = (const float*)d_in[2];
    const float* bih  = (const float*)d_in[3];
    const float* bhh  = (const float*)d_in[4];
    const float* Wout = (const float*)d_in[5];
    const float* bout = (const float*)d_in[6];
    lstm_anom_kernel<<<dim3(kB), dim3(kThreads), 0, stream>>>(
        x, Wih, Whh, bih, bhh, Wout, bout, (float*)d_out);
}